// Round 6
// baseline (152.367 us; speedup 1.0000x reference)
//
#include <hip/hip_runtime.h>
#include <hip/hip_bf16.h>
#include <math.h>

// Problem: B=4, L=2048 (M = 8192 rows), D_MODEL = 768, N_STATE = 16.
// y[row,d] = x[row,d] * softplus((x@W1+b1)[row,d]) * dot(x@W2+b2, x@W3+b3)[row]
// (dA*h0 term is identically zero; A unused.)
// Timed window carries ~62 us of harness overhead (268 MB d_ws 0xAA poison
// + d_out poison + input restores); kernel-side budget is what we optimize.

#define M_ROWS 8192
#define DM 768
#define NS 16

typedef short bf16x8 __attribute__((ext_vector_type(8)));
typedef float f32x4 __attribute__((ext_vector_type(4)));

__device__ __forceinline__ unsigned short f2bf(float f) {
    union { float f; unsigned u; } v; v.f = f;
    unsigned r = v.u + 0x7FFF + ((v.u >> 16) & 1);   // RNE
    return (unsigned short)(r >> 16);
}
__device__ __forceinline__ float bf2f(unsigned short h) {
    union { unsigned u; float f; } v; v.u = ((unsigned)h) << 16; return v.f;
}
__device__ __forceinline__ void async16(const void* g, void* l) {
    __builtin_amdgcn_global_load_lds(
        (const __attribute__((address_space(1))) void*)g,
        (__attribute__((address_space(3))) void*)l,
        16, 0, 0);
}

// ---- kernel A: prep + s, block-specialized ------------------------------
// bid [0,128):   s-blocks. 64 rows each, 4 waves x 16 rows. Reads x fp32
//                directly with the A-fragment pattern (lane=(l15,quad):
//                row=base+l15, k=kk*32+quad*8), converts in-register to the
//                MFMA A-frag AND stores it to xb (so x is read exactly once
//                machine-wide). B-tile (32 pair-interleaved cols of W2/W3)
//                staged per k-step into LDS from fp32 with the same XOR
//                swizzle the reader uses. s epilogue = verified R4 algebra.
// bid [128,704): W1 [k][n] fp32 -> w1t [n][k] bf16 (32x32 LDS tiles).
__global__ __launch_bounds__(256) void prep_s_kernel(
    const float* __restrict__ x,
    const float* __restrict__ W1,
    const float* __restrict__ W2, const float* __restrict__ b2,
    const float* __restrict__ W3, const float* __restrict__ b3,
    unsigned short* __restrict__ xb,
    unsigned short* __restrict__ w1t,
    float* __restrict__ s_out)
{
    __shared__ unsigned short Bl[32 * 64];    // 4 KB (s-blocks)
    __shared__ float tile[32][33];            // transpose blocks
    const int bid = blockIdx.x;
    const int tid = threadIdx.x;

    if (bid < 128) {
        const int wave = tid >> 6, lane = tid & 63;
        const int l15 = lane & 15, quad = lane >> 4;
        const int rowbase = bid * 64 + wave * 16;
        const int row = rowbase + l15;

        // B-staging coords: thread -> (n, k-chunk)
        const int sn = tid & 31;              // pair-interleaved col 0..31
        const int skg = tid >> 5;             // k-chunk 0..7
        const float* wsrc = ((sn & 1) ? W3 : W2) + (sn >> 1);
        const int sswz = skg ^ (sn & 7);

        f32x4 acc[2];
        acc[0] = (f32x4){0.f,0.f,0.f,0.f};
        acc[1] = (f32x4){0.f,0.f,0.f,0.f};

        for (int k0 = 0; k0 < DM; k0 += 64) {
            // stage w23 B-tile (32 x 64) from fp32 W2/W3
            {
                float v[8];
                #pragma unroll
                for (int jj = 0; jj < 8; ++jj)
                    v[jj] = wsrc[(k0 + skg * 8 + jj) * NS];
                bf16x8 bv;
                #pragma unroll
                for (int jj = 0; jj < 8; ++jj)
                    bv[jj] = (short)f2bf(v[jj]);
                *(bf16x8*)(Bl + sn * 64 + sswz * 8) = bv;
            }
            __syncthreads();
            #pragma unroll
            for (int kk = 0; kk < 2; ++kk) {
                const int kq = k0 + kk * 32 + quad * 8;
                const float4* xp = (const float4*)(x + row * DM + kq);
                float4 a0 = xp[0], a1 = xp[1];
                bf16x8 af;
                af[0] = (short)f2bf(a0.x); af[1] = (short)f2bf(a0.y);
                af[2] = (short)f2bf(a0.z); af[3] = (short)f2bf(a0.w);
                af[4] = (short)f2bf(a1.x); af[5] = (short)f2bf(a1.y);
                af[6] = (short)f2bf(a1.z); af[7] = (short)f2bf(a1.w);
                *(bf16x8*)(xb + row * DM + kq) = af;   // xb side-effect
                #pragma unroll
                for (int t = 0; t < 2; ++t) {
                    int rb = t * 16 + l15;
                    int jb = (kk * 4 + quad) ^ (rb & 7);
                    bf16x8 bfr = *(const bf16x8*)(Bl + rb * 64 + jb * 8);
                    acc[t] = __builtin_amdgcn_mfma_f32_16x16x32_bf16(
                        af, bfr, acc[t], 0, 0, 0);
                }
            }
            __syncthreads();
        }

        // s epilogue (verified): P pairs adjacent in lanes; *0.5 for the
        // double-count in the 16-lane xor reduce.
        float sacc[4] = {0.f, 0.f, 0.f, 0.f};
        #pragma unroll
        for (int t = 0; t < 2; ++t) {
            int p = t * 8 + (l15 >> 1);
            float bB = b2[p], bC = b3[p];
            #pragma unroll
            for (int r = 0; r < 4; ++r) {
                float v = acc[t][r];
                float pv = __shfl_xor(v, 1, 64);
                float term = (l15 & 1) ? (pv + bB) * (v + bC)
                                       : (v + bB) * (pv + bC);
                sacc[r] += term;
            }
        }
        #pragma unroll
        for (int r = 0; r < 4; ++r) {
            sacc[r] += __shfl_xor(sacc[r], 1, 64);
            sacc[r] += __shfl_xor(sacc[r], 2, 64);
            sacc[r] += __shfl_xor(sacc[r], 4, 64);
            sacc[r] += __shfl_xor(sacc[r], 8, 64);
        }
        if (l15 == 0) {
            #pragma unroll
            for (int r = 0; r < 4; ++r)
                s_out[rowbase + quad * 4 + r] = 0.5f * sacc[r];
        }
    } else {
        const int b2i = bid - 128;               // 0..575
        const int n0 = (b2i % 24) * 32, k0 = (b2i / 24) * 32;
        const int tx = tid & 31, ty = tid >> 5;  // 32 x 8
        #pragma unroll
        for (int i = 0; i < 4; ++i) {
            int k = ty + i * 8;
            tile[k][tx] = W1[(k0 + k) * DM + n0 + tx];
        }
        __syncthreads();
        #pragma unroll
        for (int i = 0; i < 4; ++i) {
            int n = ty + i * 8;
            w1t[(n0 + n) * DM + k0 + tx] = f2bf(tile[tx][n]);
        }
    }
}

// ---- kernel B: fused GEMM + softplus/scale epilogue ---------------------
// 128x64 block tile, BK=64, 128 threads = 2 waves, wave-tile 64x64
// (4x4 16x16x32 subtiles -> 32 MFMAs vs 16 ds_read_b128 per k-step: 2x the
// MFMA density of R5's 4-wave layout). Single-buffered 24 KB LDS -> 6
// blocks/CU, 12 waves/CU: barrier stalls hidden by inter-block overlap.
// XCD swizzle: XCD c (= b&7) covers m-tiles [c*8,c*8+8) x all 12 n-tiles.
__global__ __launch_bounds__(128, 3) void gemm_fused_kernel(
    const unsigned short* __restrict__ xb,    // [8192][768] bf16
    const unsigned short* __restrict__ w1t,   // [768][768] bf16, n-major
    const float* __restrict__ b1,
    const float* __restrict__ s_arr,
    float* __restrict__ y)
{
    __shared__ unsigned short Al[128 * 64];   // 16 KB
    __shared__ unsigned short Bl[64 * 64];    //  8 KB
    const int b = blockIdx.x;
    const int c = b & 7, j = b >> 3;          // j in [0,96)
    const int m0 = (c * 8 + j / 12) * 128;
    const int n0 = (j % 12) * 64;
    const int tid  = threadIdx.x;
    const int lane = tid & 63;
    const int w    = tid >> 6;                // wave 0,1
    const int l15 = lane & 15, quad = lane >> 4;

    f32x4 acc[4][4];
    #pragma unroll
    for (int i = 0; i < 4; ++i)
        #pragma unroll
        for (int jj = 0; jj < 4; ++jj)
            acc[i][jj] = (f32x4){0.f, 0.f, 0.f, 0.f};

    for (int k0 = 0; k0 < DM; k0 += 64) {
        #pragma unroll
        for (int i = 0; i < 8; ++i) {         // A: 1024 chunks / 128 thr
            int ch = tid + i * 128;
            int r = ch >> 3, jg = (ch & 7) ^ (r & 7);
            async16(xb + (m0 + r) * DM + k0 + jg * 8, Al + ch * 8);
        }
        #pragma unroll
        for (int i = 0; i < 4; ++i) {         // B: 512 chunks / 128 thr
            int ch = tid + i * 128;
            int r = ch >> 3, jg = (ch & 7) ^ (r & 7);
            async16(w1t + (n0 + r) * DM + k0 + jg * 8, Bl + ch * 8);
        }
        __syncthreads();

        #pragma unroll
        for (int kk = 0; kk < 2; ++kk) {
            bf16x8 bfr[4];
            #pragma unroll
            for (int jj = 0; jj < 4; ++jj) {
                int rb = jj * 16 + l15;
                int jb = (kk * 4 + quad) ^ (rb & 7);
                bfr[jj] = *(const bf16x8*)(Bl + rb * 64 + jb * 8);
            }
            #pragma unroll
            for (int i = 0; i < 4; ++i) {
                int rr = w * 64 + i * 16 + l15;
                int ja = (kk * 4 + quad) ^ (rr & 7);
                bf16x8 af = *(const bf16x8*)(Al + rr * 64 + ja * 8);
                #pragma unroll
                for (int jj = 0; jj < 4; ++jj)
                    acc[i][jj] = __builtin_amdgcn_mfma_f32_16x16x32_bf16(
                        af, bfr[jj], acc[i][jj], 0, 0, 0);
            }
        }
        __syncthreads();
    }

    // epilogue: C/D layout col = lane&15, row = quad*4 + reg
    #pragma unroll
    for (int i = 0; i < 4; ++i) {
        const int rowbase = m0 + w * 64 + i * 16 + quad * 4;
        float4 s4 = *(const float4*)(s_arr + rowbase);
        #pragma unroll
        for (int jj = 0; jj < 4; ++jj) {
            int gcol = n0 + jj * 16 + l15;
            float bias = b1[gcol];
            #pragma unroll
            for (int r = 0; r < 4; ++r) {
                int grow = rowbase + r;
                float v = acc[i][jj][r] + bias;
                float sp = (v > 20.f) ? v : log1pf(__expf(v));
                float xv = bf2f(xb[grow * DM + gcol]);
                float sv = (r == 0) ? s4.x : (r == 1) ? s4.y : (r == 2) ? s4.z : s4.w;
                y[grow * DM + gcol] = xv * sp * sv;
            }
        }
    }
}

extern "C" void kernel_launch(void* const* d_in, const int* in_sizes, int n_in,
                              void* d_out, int out_size, void* d_ws, size_t ws_size,
                              hipStream_t stream) {
    const float* x  = (const float*)d_in[0];
    const float* W1 = (const float*)d_in[1];
    const float* b1 = (const float*)d_in[2];
    const float* W2 = (const float*)d_in[3];
    const float* b2 = (const float*)d_in[4];
    const float* W3 = (const float*)d_in[5];
    const float* b3 = (const float*)d_in[6];
    // d_in[7] = A : unused (multiplied by h0 == 0 in the reference)
    float* y = (float*)d_out;

    unsigned short* xb   = (unsigned short*)d_ws;                      // 12,582,912 B
    unsigned short* w1t  = (unsigned short*)((char*)d_ws + 12582912);  //  1,179,648 B
    float*          sarr = (float*)((char*)d_ws + 13762560);           //     32,768 B

    prep_s_kernel<<<704, 256, 0, stream>>>(x, W1, W2, b2, W3, b3,
                                           xb, w1t, sarr);
    gemm_fused_kernel<<<768, 128, 0, stream>>>(xb, w1t, b1, sarr, y);
}

// Round 7
// 139.473 us; speedup vs baseline: 1.0925x; 1.0925x over previous
//
#include <hip/hip_runtime.h>
#include <hip/hip_bf16.h>
#include <math.h>

// Problem: B=4, L=2048 (M = 8192 rows), D_MODEL = 768, N_STATE = 16.
// y[row,d] = x[row,d] * softplus((x@W1+b1)[row,d]) * dot(x@W2+b2, x@W3+b3)[row]
// (dA*h0 term is identically zero; A unused.)
// Known-good anchor: R5 = 135.8 us total (dbuf 4-wave gemm). R6's 2-wave
// gemm regressed to 133 us profiled (6 waves/CU, latency-starved) -> reverted.

#define M_ROWS 8192
#define DM 768
#define NS 16

typedef short bf16x8 __attribute__((ext_vector_type(8)));
typedef float f32x4 __attribute__((ext_vector_type(4)));

__device__ __forceinline__ unsigned short f2bf(float f) {
    union { float f; unsigned u; } v; v.f = f;
    unsigned r = v.u + 0x7FFF + ((v.u >> 16) & 1);   // RNE
    return (unsigned short)(r >> 16);
}
__device__ __forceinline__ float bf2f(unsigned short h) {
    union { unsigned u; float f; } v; v.u = ((unsigned)h) << 16; return v.f;
}
__device__ __forceinline__ void async16(const void* g, void* l) {
    __builtin_amdgcn_global_load_lds(
        (const __attribute__((address_space(1))) void*)g,
        (__attribute__((address_space(3))) void*)l,
        16, 0, 0);
}

// ---- kernel A: prep + s, block-specialized ------------------------------
// bid [0,128):   s-blocks. 64 rows, 4 waves x 16 rows. Stage ALL of W2/W3
//                (pair-interleaved, 32 x 768 bf16 = 48 KB) into LDS ONCE,
//                then a barrier-free k-loop: read x fp32 in A-frag pattern,
//                cvt in-register (also storing xb -- x read once machine-
//                wide), 4 MFMAs per k-step. s epilogue = verified algebra.
// bid [128,704): W1 [k][n] fp32 -> w1t [n][k] bf16 (32x32 LDS tiles).
__global__ __launch_bounds__(256) void prep_s_kernel(
    const float* __restrict__ x,
    const float* __restrict__ W1,
    const float* __restrict__ W2, const float* __restrict__ b2,
    const float* __restrict__ W3, const float* __restrict__ b3,
    unsigned short* __restrict__ xb,
    unsigned short* __restrict__ w1t,
    float* __restrict__ s_out)
{
    __shared__ unsigned short Bl[12][32 * 64];   // 48 KB: 12 k-windows
    __shared__ float tile[32][33];               // transpose blocks
    const int bid = blockIdx.x;
    const int tid = threadIdx.x;

    if (bid < 128) {
        const int wave = tid >> 6, lane = tid & 63;
        const int l15 = lane & 15, quad = lane >> 4;
        const int rowbase = bid * 64 + wave * 16;
        const int row = rowbase + l15;

        // ---- one-time staging of all W2/W3 into LDS ----
        // thread -> (n, chunk): 32 n x 8 chunks per window, 12 windows.
        const int sn = tid & 31;              // pair-interleaved col 0..31
        const int skg = tid >> 5;             // k-chunk 0..7
        const float* wsrc = ((sn & 1) ? W3 : W2) + (sn >> 1);
        const int sswz = skg ^ (sn & 7);
        for (int w = 0; w < 12; ++w) {
            float v[8];
            #pragma unroll
            for (int jj = 0; jj < 8; ++jj)
                v[jj] = wsrc[(w * 64 + skg * 8 + jj) * NS];
            bf16x8 bv;
            #pragma unroll
            for (int jj = 0; jj < 8; ++jj)
                bv[jj] = (short)f2bf(v[jj]);
            *(bf16x8*)(&Bl[w][sn * 64 + sswz * 8]) = bv;
        }
        __syncthreads();   // the only barrier in the s-path

        f32x4 acc[2];
        acc[0] = (f32x4){0.f,0.f,0.f,0.f};
        acc[1] = (f32x4){0.f,0.f,0.f,0.f};

        for (int w = 0; w < 12; ++w) {
            #pragma unroll
            for (int kk = 0; kk < 2; ++kk) {
                const int kq = w * 64 + kk * 32 + quad * 8;
                const float4* xp = (const float4*)(x + row * DM + kq);
                float4 a0 = xp[0], a1 = xp[1];
                bf16x8 af;
                af[0] = (short)f2bf(a0.x); af[1] = (short)f2bf(a0.y);
                af[2] = (short)f2bf(a0.z); af[3] = (short)f2bf(a0.w);
                af[4] = (short)f2bf(a1.x); af[5] = (short)f2bf(a1.y);
                af[6] = (short)f2bf(a1.z); af[7] = (short)f2bf(a1.w);
                *(bf16x8*)(xb + row * DM + kq) = af;   // xb side-effect
                #pragma unroll
                for (int t = 0; t < 2; ++t) {
                    int rb = t * 16 + l15;
                    int jb = (kk * 4 + quad) ^ (rb & 7);
                    bf16x8 bfr = *(const bf16x8*)(&Bl[w][rb * 64 + jb * 8]);
                    acc[t] = __builtin_amdgcn_mfma_f32_16x16x32_bf16(
                        af, bfr, acc[t], 0, 0, 0);
                }
            }
        }

        // s epilogue (verified): pair products adjacent in lanes; *0.5 for
        // the double-count in the 16-lane xor reduce.
        float sacc[4] = {0.f, 0.f, 0.f, 0.f};
        #pragma unroll
        for (int t = 0; t < 2; ++t) {
            int p = t * 8 + (l15 >> 1);
            float bB = b2[p], bC = b3[p];
            #pragma unroll
            for (int r = 0; r < 4; ++r) {
                float v = acc[t][r];
                float pv = __shfl_xor(v, 1, 64);
                float term = (l15 & 1) ? (pv + bB) * (v + bC)
                                       : (v + bB) * (pv + bC);
                sacc[r] += term;
            }
        }
        #pragma unroll
        for (int r = 0; r < 4; ++r) {
            sacc[r] += __shfl_xor(sacc[r], 1, 64);
            sacc[r] += __shfl_xor(sacc[r], 2, 64);
            sacc[r] += __shfl_xor(sacc[r], 4, 64);
            sacc[r] += __shfl_xor(sacc[r], 8, 64);
        }
        if (l15 == 0) {
            #pragma unroll
            for (int r = 0; r < 4; ++r)
                s_out[rowbase + quad * 4 + r] = 0.5f * sacc[r];
        }
    } else {
        const int b2i = bid - 128;               // 0..575
        const int n0 = (b2i % 24) * 32, k0 = (b2i / 24) * 32;
        const int tx = tid & 31, ty = tid >> 5;  // 32 x 8
        #pragma unroll
        for (int i = 0; i < 4; ++i) {
            int k = ty + i * 8;
            tile[k][tx] = W1[(k0 + k) * DM + n0 + tx];
        }
        __syncthreads();
        #pragma unroll
        for (int i = 0; i < 4; ++i) {
            int n = ty + i * 8;
            w1t[(n0 + n) * DM + k0 + tx] = f2bf(tile[tx][n]);
        }
    }
}

// ---- kernel B: fused GEMM (R5-exact revert) -----------------------------
// 128x64 tile, BK=64, 256 threads (4 waves 2x2, wave-tile 64x32), double-
// buffered 48 KB LDS -> 3 blocks/CU = 12 waves/CU. 768 blocks, XCD swizzle.
// R6 lesson: waves/CU is the controlling variable, not MFMA density per
// staged byte -- 2-wave blocks (6 waves/CU) were 2-4x slower.
__global__ __launch_bounds__(256) void gemm_fused_kernel(
    const unsigned short* __restrict__ xb,    // [8192][768] bf16
    const unsigned short* __restrict__ w1t,   // [768][768] bf16, n-major
    const float* __restrict__ b1,
    const float* __restrict__ s_arr,
    float* __restrict__ y)
{
    __shared__ unsigned short Al[2][128 * 64];   // 2 x 16 KB
    __shared__ unsigned short Bl[2][64 * 64];    // 2 x  8 KB
    const int b = blockIdx.x;
    const int c = b & 7, j = b >> 3;             // j in [0,96)
    const int m0 = (c * 8 + j / 12) * 128;
    const int n0 = (j % 12) * 64;
    const int tid  = threadIdx.x;
    const int lane = tid & 63;
    const int wave = tid >> 6;
    const int wm = wave >> 1, wn = wave & 1;
    const int l15 = lane & 15, quad = lane >> 4;

    f32x4 acc[4][2];
    #pragma unroll
    for (int i = 0; i < 4; ++i)
        #pragma unroll
        for (int jj = 0; jj < 2; ++jj)
            acc[i][jj] = (f32x4){0.f, 0.f, 0.f, 0.f};

    // stage k-step 0 into buffer 0
    {
        #pragma unroll
        for (int i = 0; i < 4; ++i) {
            int ch = tid + i * 256;
            int r = ch >> 3, jg = (ch & 7) ^ (r & 7);
            async16(xb + (m0 + r) * DM + jg * 8, &Al[0][ch * 8]);
        }
        #pragma unroll
        for (int i = 0; i < 2; ++i) {
            int ch = tid + i * 256;
            int r = ch >> 3, jg = (ch & 7) ^ (r & 7);
            async16(w1t + (n0 + r) * DM + jg * 8, &Bl[0][ch * 8]);
        }
    }

    for (int step = 0; step < DM / 64; ++step) {
        const int cur = step & 1;
        __syncthreads();   // drains this step's loads (in flight since last compute)

        if (step + 1 < DM / 64) {
            const int k0 = (step + 1) * 64;
            const int nxt = cur ^ 1;
            #pragma unroll
            for (int i = 0; i < 4; ++i) {
                int ch = tid + i * 256;
                int r = ch >> 3, jg = (ch & 7) ^ (r & 7);
                async16(xb + (m0 + r) * DM + k0 + jg * 8, &Al[nxt][ch * 8]);
            }
            #pragma unroll
            for (int i = 0; i < 2; ++i) {
                int ch = tid + i * 256;
                int r = ch >> 3, jg = (ch & 7) ^ (r & 7);
                async16(w1t + (n0 + r) * DM + k0 + jg * 8, &Bl[nxt][ch * 8]);
            }
        }

        #pragma unroll
        for (int kk = 0; kk < 2; ++kk) {
            bf16x8 bfr[2];
            #pragma unroll
            for (int jj = 0; jj < 2; ++jj) {
                int rb = wn * 32 + jj * 16 + l15;
                int jb = (kk * 4 + quad) ^ (rb & 7);
                bfr[jj] = *(const bf16x8*)(&Bl[cur][rb * 64 + jb * 8]);
            }
            #pragma unroll
            for (int i = 0; i < 4; ++i) {
                int rr = wm * 64 + i * 16 + l15;
                int ja = (kk * 4 + quad) ^ (rr & 7);
                bf16x8 af = *(const bf16x8*)(&Al[cur][rr * 64 + ja * 8]);
                #pragma unroll
                for (int jj = 0; jj < 2; ++jj)
                    acc[i][jj] = __builtin_amdgcn_mfma_f32_16x16x32_bf16(
                        af, bfr[jj], acc[i][jj], 0, 0, 0);
            }
        }
    }

    // epilogue: C/D layout col = lane&15, row = quad*4 + reg
    #pragma unroll
    for (int i = 0; i < 4; ++i) {
        const int rowbase = m0 + wm * 64 + i * 16 + quad * 4;
        float4 s4 = *(const float4*)(s_arr + rowbase);
        #pragma unroll
        for (int jj = 0; jj < 2; ++jj) {
            int gcol = n0 + wn * 32 + jj * 16 + l15;
            float bias = b1[gcol];
            #pragma unroll
            for (int r = 0; r < 4; ++r) {
                int grow = rowbase + r;
                float v = acc[i][jj][r] + bias;
                float sp = (v > 20.f) ? v : log1pf(__expf(v));
                float xv = bf2f(xb[grow * DM + gcol]);
                float sv = (r == 0) ? s4.x : (r == 1) ? s4.y : (r == 2) ? s4.z : s4.w;
                y[grow * DM + gcol] = xv * sp * sv;
            }
        }
    }
}

extern "C" void kernel_launch(void* const* d_in, const int* in_sizes, int n_in,
                              void* d_out, int out_size, void* d_ws, size_t ws_size,
                              hipStream_t stream) {
    const float* x  = (const float*)d_in[0];
    const float* W1 = (const float*)d_in[1];
    const float* b1 = (const float*)d_in[2];
    const float* W2 = (const float*)d_in[3];
    const float* b2 = (const float*)d_in[4];
    const float* W3 = (const float*)d_in[5];
    const float* b3 = (const float*)d_in[6];
    // d_in[7] = A : unused (multiplied by h0 == 0 in the reference)
    float* y = (float*)d_out;

    unsigned short* xb   = (unsigned short*)d_ws;                      // 12,582,912 B
    unsigned short* w1t  = (unsigned short*)((char*)d_ws + 12582912);  //  1,179,648 B
    float*          sarr = (float*)((char*)d_ws + 13762560);           //     32,768 B

    prep_s_kernel<<<704, 256, 0, stream>>>(x, W1, W2, b2, W3, b3,
                                           xb, w1t, sarr);
    gemm_fused_kernel<<<768, 256, 0, stream>>>(xb, w1t, b1, sarr, y);
}

// Round 8
// 116.497 us; speedup vs baseline: 1.3079x; 1.1972x over previous
//
#include <hip/hip_runtime.h>
#include <hip/hip_bf16.h>
#include <math.h>

// Problem: B=4, L=2048 (M = 8192 rows), D_MODEL = 768, N_STATE = 16.
// y[row,d] = x[row,d] * softplus((x@W1+b1)[row,d]) * dot(x@W2+b2, x@W3+b3)[row]
// (dA*h0 term is identically zero; A unused.)
// Ledger (profiled): ~62 us harness fills (fixed) + gemm + prep/sgemm.
// R7: gemm 44 us was VALU-bound on libm log1pf in the epilogue -> fast
// softplus here. Prep split (R5 style) beats merged prep_s by ~5 us.

#define M_ROWS 8192
#define DM 768
#define NS 16

typedef short bf16x8 __attribute__((ext_vector_type(8)));
typedef float f32x4 __attribute__((ext_vector_type(4)));

__device__ __forceinline__ unsigned short f2bf(float f) {
    union { float f; unsigned u; } v; v.f = f;
    unsigned r = v.u + 0x7FFF + ((v.u >> 16) & 1);   // RNE
    return (unsigned short)(r >> 16);
}
__device__ __forceinline__ float bf2f(unsigned short h) {
    union { unsigned u; float f; } v; v.u = ((unsigned)h) << 16; return v.f;
}
__device__ __forceinline__ void async16(const void* g, void* l) {
    __builtin_amdgcn_global_load_lds(
        (const __attribute__((address_space(1))) void*)g,
        (__attribute__((address_space(3))) void*)l,
        16, 0, 0);
}
// branchless stable softplus: max(v,0) + log(1+exp(-|v|)); HW exp/log.
__device__ __forceinline__ float softplus_fast(float v) {
    return fmaxf(v, 0.f) + __logf(1.f + __expf(-fabsf(v)));
}

// ---- kernel 1: prep (pure streaming, block-specialized; R5-exact) -------
__global__ __launch_bounds__(256) void prep_kernel(
    const float* __restrict__ x,
    const float* __restrict__ W1,
    const float* __restrict__ W2,
    const float* __restrict__ W3,
    unsigned short* __restrict__ xb,
    unsigned short* __restrict__ w1t,
    unsigned short* __restrict__ w23t)
{
    __shared__ float tile[32][33];
    const int bid = blockIdx.x;
    const int tid = threadIdx.x;
    if (bid < 32) {
        const int n = bid, i = n >> 1;
        const float* src = (n & 1) ? W3 : W2;
        #pragma unroll
        for (int e = 0; e < 3; ++e) {
            int k = e * 256 + tid;
            w23t[n * DM + k] = f2bf(src[k * NS + i]);
        }
    } else if (bid < 608) {
        const int b2i = bid - 32;                // 0..575
        const int n0 = (b2i % 24) * 32, k0 = (b2i / 24) * 32;
        const int tx = tid & 31, ty = tid >> 5;  // 32 x 8
        #pragma unroll
        for (int i = 0; i < 4; ++i) {
            int k = ty + i * 8;
            tile[k][tx] = W1[(k0 + k) * DM + n0 + tx];
        }
        __syncthreads();
        #pragma unroll
        for (int i = 0; i < 4; ++i) {
            int n = ty + i * 8;
            w1t[(n0 + n) * DM + k0 + tx] = f2bf(tile[tx][n]);
        }
    } else {
        int i = (bid - 608) * 256 + tid;         // one float4 per thread
        float4 v = ((const float4*)x)[i];
        ushort4 o;
        o.x = f2bf(v.x); o.y = f2bf(v.y); o.z = f2bf(v.z); o.w = f2bf(v.w);
        ((ushort4*)xb)[i] = o;
    }
}

// ---- kernel 2: s via MFMA (R4/R5-exact, verified) -----------------------
__global__ __launch_bounds__(256) void sgemm_kernel(
    const unsigned short* __restrict__ xb,
    const unsigned short* __restrict__ w23t,
    const float* __restrict__ b2, const float* __restrict__ b3,
    float* __restrict__ s_out)
{
    __shared__ unsigned short Al[64 * 64];
    __shared__ unsigned short Bl[32 * 64];
    const int m0 = blockIdx.x * 64;
    const int tid = threadIdx.x, lane = tid & 63, wave = tid >> 6;
    const int l15 = lane & 15, quad = lane >> 4;

    f32x4 acc[2];
    acc[0] = (f32x4){0.f,0.f,0.f,0.f};
    acc[1] = (f32x4){0.f,0.f,0.f,0.f};

    for (int k0 = 0; k0 < DM; k0 += 64) {
        #pragma unroll
        for (int i = 0; i < 2; ++i) {
            int ch = tid + i * 256;
            int r = ch >> 3, jg = (ch & 7) ^ (r & 7);
            async16(xb + (m0 + r) * DM + k0 + jg * 8, Al + ch * 8);
        }
        {
            int ch = tid;
            int r = ch >> 3, jg = (ch & 7) ^ (r & 7);
            async16(w23t + r * DM + k0 + jg * 8, Bl + ch * 8);
        }
        __syncthreads();
        #pragma unroll
        for (int kk = 0; kk < 2; ++kk) {
            int rr = wave * 16 + l15;
            int ja = (kk * 4 + quad) ^ (rr & 7);
            bf16x8 af = *(const bf16x8*)(Al + rr * 64 + ja * 8);
            #pragma unroll
            for (int t = 0; t < 2; ++t) {
                int rb = t * 16 + l15;
                int jb = (kk * 4 + quad) ^ (rb & 7);
                bf16x8 bfr = *(const bf16x8*)(Bl + rb * 64 + jb * 8);
                acc[t] = __builtin_amdgcn_mfma_f32_16x16x32_bf16(
                    af, bfr, acc[t], 0, 0, 0);
            }
        }
        __syncthreads();
    }

    float sacc[4] = {0.f, 0.f, 0.f, 0.f};
    #pragma unroll
    for (int t = 0; t < 2; ++t) {
        int p = t * 8 + (l15 >> 1);
        float bB = b2[p], bC = b3[p];
        #pragma unroll
        for (int r = 0; r < 4; ++r) {
            float v = acc[t][r];
            float pv = __shfl_xor(v, 1, 64);
            float term = (l15 & 1) ? (pv + bB) * (v + bC)
                                   : (v + bB) * (pv + bC);
            sacc[r] += term;
        }
    }
    #pragma unroll
    for (int r = 0; r < 4; ++r) {
        sacc[r] += __shfl_xor(sacc[r], 1, 64);
        sacc[r] += __shfl_xor(sacc[r], 2, 64);
        sacc[r] += __shfl_xor(sacc[r], 4, 64);
        sacc[r] += __shfl_xor(sacc[r], 8, 64);
    }
    if (l15 == 0) {
        #pragma unroll
        for (int r = 0; r < 4; ++r)
            s_out[m0 + wave * 16 + quad * 4 + r] = 0.5f * sacc[r];
    }
}

// ---- kernel 3: fused GEMM, dbuf (R5 structure) + fast-softplus epilogue -
// 128x64 tile, BK=64, 256 thr (4 waves 2x2), dbuf 48 KB LDS -> 3 blocks/CU
// = 12 waves/CU (R6 lesson: waves/CU is the controlling variable). 768
// blocks, XCD swizzle. R7 lesson: epilogue log1pf was ~half the kernel's
// VALU -> softplus_fast.
__global__ __launch_bounds__(256) void gemm_fused_kernel(
    const unsigned short* __restrict__ xb,    // [8192][768] bf16
    const unsigned short* __restrict__ w1t,   // [768][768] bf16, n-major
    const float* __restrict__ b1,
    const float* __restrict__ s_arr,
    float* __restrict__ y)
{
    __shared__ unsigned short Al[2][128 * 64];   // 2 x 16 KB
    __shared__ unsigned short Bl[2][64 * 64];    // 2 x  8 KB
    const int b = blockIdx.x;
    const int c = b & 7, j = b >> 3;             // j in [0,96)
    const int m0 = (c * 8 + j / 12) * 128;
    const int n0 = (j % 12) * 64;
    const int tid  = threadIdx.x;
    const int lane = tid & 63;
    const int wave = tid >> 6;
    const int wm = wave >> 1, wn = wave & 1;
    const int l15 = lane & 15, quad = lane >> 4;

    f32x4 acc[4][2];
    #pragma unroll
    for (int i = 0; i < 4; ++i)
        #pragma unroll
        for (int jj = 0; jj < 2; ++jj)
            acc[i][jj] = (f32x4){0.f, 0.f, 0.f, 0.f};

    // stage k-step 0 into buffer 0
    {
        #pragma unroll
        for (int i = 0; i < 4; ++i) {
            int ch = tid + i * 256;
            int r = ch >> 3, jg = (ch & 7) ^ (r & 7);
            async16(xb + (m0 + r) * DM + jg * 8, &Al[0][ch * 8]);
        }
        #pragma unroll
        for (int i = 0; i < 2; ++i) {
            int ch = tid + i * 256;
            int r = ch >> 3, jg = (ch & 7) ^ (r & 7);
            async16(w1t + (n0 + r) * DM + jg * 8, &Bl[0][ch * 8]);
        }
    }

    for (int step = 0; step < DM / 64; ++step) {
        const int cur = step & 1;
        __syncthreads();

        if (step + 1 < DM / 64) {
            const int k0 = (step + 1) * 64;
            const int nxt = cur ^ 1;
            #pragma unroll
            for (int i = 0; i < 4; ++i) {
                int ch = tid + i * 256;
                int r = ch >> 3, jg = (ch & 7) ^ (r & 7);
                async16(xb + (m0 + r) * DM + k0 + jg * 8, &Al[nxt][ch * 8]);
            }
            #pragma unroll
            for (int i = 0; i < 2; ++i) {
                int ch = tid + i * 256;
                int r = ch >> 3, jg = (ch & 7) ^ (r & 7);
                async16(w1t + (n0 + r) * DM + k0 + jg * 8, &Bl[nxt][ch * 8]);
            }
        }

        #pragma unroll
        for (int kk = 0; kk < 2; ++kk) {
            bf16x8 bfr[2];
            #pragma unroll
            for (int jj = 0; jj < 2; ++jj) {
                int rb = wn * 32 + jj * 16 + l15;
                int jb = (kk * 4 + quad) ^ (rb & 7);
                bfr[jj] = *(const bf16x8*)(&Bl[cur][rb * 64 + jb * 8]);
            }
            #pragma unroll
            for (int i = 0; i < 4; ++i) {
                int rr = wm * 64 + i * 16 + l15;
                int ja = (kk * 4 + quad) ^ (rr & 7);
                bf16x8 af = *(const bf16x8*)(&Al[cur][rr * 64 + ja * 8]);
                #pragma unroll
                for (int jj = 0; jj < 2; ++jj)
                    acc[i][jj] = __builtin_amdgcn_mfma_f32_16x16x32_bf16(
                        af, bfr[jj], acc[i][jj], 0, 0, 0);
            }
        }
    }

    // epilogue: C/D layout col = lane&15, row = quad*4 + reg
    #pragma unroll
    for (int i = 0; i < 4; ++i) {
        const int rowbase = m0 + wm * 64 + i * 16 + quad * 4;
        float4 s4 = *(const float4*)(s_arr + rowbase);
        #pragma unroll
        for (int jj = 0; jj < 2; ++jj) {
            int gcol = n0 + wn * 32 + jj * 16 + l15;
            float bias = b1[gcol];
            #pragma unroll
            for (int r = 0; r < 4; ++r) {
                int grow = rowbase + r;
                float v = acc[i][jj][r] + bias;
                float sp = softplus_fast(v);
                float xv = bf2f(xb[grow * DM + gcol]);
                float sv = (r == 0) ? s4.x : (r == 1) ? s4.y : (r == 2) ? s4.z : s4.w;
                y[grow * DM + gcol] = xv * sp * sv;
            }
        }
    }
}

extern "C" void kernel_launch(void* const* d_in, const int* in_sizes, int n_in,
                              void* d_out, int out_size, void* d_ws, size_t ws_size,
                              hipStream_t stream) {
    const float* x  = (const float*)d_in[0];
    const float* W1 = (const float*)d_in[1];
    const float* b1 = (const float*)d_in[2];
    const float* W2 = (const float*)d_in[3];
    const float* b2 = (const float*)d_in[4];
    const float* W3 = (const float*)d_in[5];
    const float* b3 = (const float*)d_in[6];
    // d_in[7] = A : unused (multiplied by h0 == 0 in the reference)
    float* y = (float*)d_out;

    unsigned short* xb   = (unsigned short*)d_ws;                      // 12,582,912 B
    unsigned short* w1t  = (unsigned short*)((char*)d_ws + 12582912);  //  1,179,648 B
    unsigned short* w23t = (unsigned short*)((char*)d_ws + 13762560);  //     49,152 B
    float*          sarr = (float*)((char*)d_ws + 13811712);           //     32,768 B

    prep_kernel<<<6752, 256, 0, stream>>>(x, W1, W2, W3, xb, w1t, w23t);
    sgemm_kernel<<<128, 256, 0, stream>>>(xb, w23t, b2, b3, sarr);
    gemm_fused_kernel<<<768, 256, 0, stream>>>(xb, w1t, b1, sarr, y);
}

// Round 9
// 116.363 us; speedup vs baseline: 1.3094x; 1.0011x over previous
//
#include <hip/hip_runtime.h>
#include <hip/hip_bf16.h>
#include <math.h>

// Problem: B=4, L=2048 (M = 8192 rows), D_MODEL = 768, N_STATE = 16.
// y[row,d] = x[row,d] * softplus((x@W1+b1)[row,d]) * dot(x@W2+b2, x@W3+b3)[row]
// (dA*h0 term is identically zero; A unused.)
// Ledger (R8): 116.5 total = ~62 harness fills (fixed) + gemm ~30 + prep ~13
// + sgemm ~6 + gaps. R9: single-buffer gemm -> 6 blocks/CU for latency hiding.

#define M_ROWS 8192
#define DM 768
#define NS 16

typedef short bf16x8 __attribute__((ext_vector_type(8)));
typedef float f32x4 __attribute__((ext_vector_type(4)));

__device__ __forceinline__ unsigned short f2bf(float f) {
    union { float f; unsigned u; } v; v.f = f;
    unsigned r = v.u + 0x7FFF + ((v.u >> 16) & 1);   // RNE
    return (unsigned short)(r >> 16);
}
__device__ __forceinline__ float bf2f(unsigned short h) {
    union { unsigned u; float f; } v; v.u = ((unsigned)h) << 16; return v.f;
}
__device__ __forceinline__ void async16(const void* g, void* l) {
    __builtin_amdgcn_global_load_lds(
        (const __attribute__((address_space(1))) void*)g,
        (__attribute__((address_space(3))) void*)l,
        16, 0, 0);
}
// branchless stable softplus: max(v,0) + log(1+exp(-|v|)); HW exp/log.
__device__ __forceinline__ float softplus_fast(float v) {
    return fmaxf(v, 0.f) + __logf(1.f + __expf(-fabsf(v)));
}

// ---- kernel 1: prep (pure streaming, block-specialized) -----------------
__global__ __launch_bounds__(256) void prep_kernel(
    const float* __restrict__ x,
    const float* __restrict__ W1,
    const float* __restrict__ W2,
    const float* __restrict__ W3,
    unsigned short* __restrict__ xb,
    unsigned short* __restrict__ w1t,
    unsigned short* __restrict__ w23t)
{
    __shared__ float tile[32][33];
    const int bid = blockIdx.x;
    const int tid = threadIdx.x;
    if (bid < 32) {
        const int n = bid, i = n >> 1;
        const float* src = (n & 1) ? W3 : W2;
        #pragma unroll
        for (int e = 0; e < 3; ++e) {
            int k = e * 256 + tid;
            w23t[n * DM + k] = f2bf(src[k * NS + i]);
        }
    } else if (bid < 608) {
        const int b2i = bid - 32;                // 0..575
        const int n0 = (b2i % 24) * 32, k0 = (b2i / 24) * 32;
        const int tx = tid & 31, ty = tid >> 5;  // 32 x 8
        #pragma unroll
        for (int i = 0; i < 4; ++i) {
            int k = ty + i * 8;
            tile[k][tx] = W1[(k0 + k) * DM + n0 + tx];
        }
        __syncthreads();
        #pragma unroll
        for (int i = 0; i < 4; ++i) {
            int n = ty + i * 8;
            w1t[(n0 + n) * DM + k0 + tx] = f2bf(tile[tx][n]);
        }
    } else {
        int i = (bid - 608) * 256 + tid;         // one float4 per thread
        float4 v = ((const float4*)x)[i];
        ushort4 o;
        o.x = f2bf(v.x); o.y = f2bf(v.y); o.z = f2bf(v.z); o.w = f2bf(v.w);
        ((ushort4*)xb)[i] = o;
    }
}

// ---- kernel 2: s via MFMA (verified) ------------------------------------
__global__ __launch_bounds__(256) void sgemm_kernel(
    const unsigned short* __restrict__ xb,
    const unsigned short* __restrict__ w23t,
    const float* __restrict__ b2, const float* __restrict__ b3,
    float* __restrict__ s_out)
{
    __shared__ unsigned short Al[64 * 64];
    __shared__ unsigned short Bl[32 * 64];
    const int m0 = blockIdx.x * 64;
    const int tid = threadIdx.x, lane = tid & 63, wave = tid >> 6;
    const int l15 = lane & 15, quad = lane >> 4;

    f32x4 acc[2];
    acc[0] = (f32x4){0.f,0.f,0.f,0.f};
    acc[1] = (f32x4){0.f,0.f,0.f,0.f};

    for (int k0 = 0; k0 < DM; k0 += 64) {
        #pragma unroll
        for (int i = 0; i < 2; ++i) {
            int ch = tid + i * 256;
            int r = ch >> 3, jg = (ch & 7) ^ (r & 7);
            async16(xb + (m0 + r) * DM + k0 + jg * 8, Al + ch * 8);
        }
        {
            int ch = tid;
            int r = ch >> 3, jg = (ch & 7) ^ (r & 7);
            async16(w23t + r * DM + k0 + jg * 8, Bl + ch * 8);
        }
        __syncthreads();
        #pragma unroll
        for (int kk = 0; kk < 2; ++kk) {
            int rr = wave * 16 + l15;
            int ja = (kk * 4 + quad) ^ (rr & 7);
            bf16x8 af = *(const bf16x8*)(Al + rr * 64 + ja * 8);
            #pragma unroll
            for (int t = 0; t < 2; ++t) {
                int rb = t * 16 + l15;
                int jb = (kk * 4 + quad) ^ (rb & 7);
                bf16x8 bfr = *(const bf16x8*)(Bl + rb * 64 + jb * 8);
                acc[t] = __builtin_amdgcn_mfma_f32_16x16x32_bf16(
                    af, bfr, acc[t], 0, 0, 0);
            }
        }
        __syncthreads();
    }

    float sacc[4] = {0.f, 0.f, 0.f, 0.f};
    #pragma unroll
    for (int t = 0; t < 2; ++t) {
        int p = t * 8 + (l15 >> 1);
        float bB = b2[p], bC = b3[p];
        #pragma unroll
        for (int r = 0; r < 4; ++r) {
            float v = acc[t][r];
            float pv = __shfl_xor(v, 1, 64);
            float term = (l15 & 1) ? (pv + bB) * (v + bC)
                                   : (v + bB) * (pv + bC);
            sacc[r] += term;
        }
    }
    #pragma unroll
    for (int r = 0; r < 4; ++r) {
        sacc[r] += __shfl_xor(sacc[r], 1, 64);
        sacc[r] += __shfl_xor(sacc[r], 2, 64);
        sacc[r] += __shfl_xor(sacc[r], 4, 64);
        sacc[r] += __shfl_xor(sacc[r], 8, 64);
    }
    if (l15 == 0) {
        #pragma unroll
        for (int r = 0; r < 4; ++r)
            s_out[m0 + wave * 16 + quad * 4 + r] = 0.5f * sacc[r];
    }
}

// ---- kernel 3: fused GEMM, single-buffered, 6 blocks/CU -----------------
// 128x64 tile, BK=64, 256 thr (4 waves 2x2), 24 KB LDS -> 6 blocks/CU =
// 24 waves/CU: per-step staging latency (xb/w1t are L2/L3-resident,
// ~200-400 cyc) hidden by 6 independent step-machines per CU. Fast
// softplus epilogue (R8 win). 768 blocks, XCD swizzle.
__global__ __launch_bounds__(256) void gemm_fused_kernel(
    const unsigned short* __restrict__ xb,    // [8192][768] bf16
    const unsigned short* __restrict__ w1t,   // [768][768] bf16, n-major
    const float* __restrict__ b1,
    const float* __restrict__ s_arr,
    float* __restrict__ y)
{
    __shared__ unsigned short Al[128 * 64];   // 16 KB
    __shared__ unsigned short Bl[64 * 64];    //  8 KB
    const int b = blockIdx.x;
    const int c = b & 7, j = b >> 3;          // j in [0,96)
    const int m0 = (c * 8 + j / 12) * 128;
    const int n0 = (j % 12) * 64;
    const int tid  = threadIdx.x;
    const int lane = tid & 63;
    const int wave = tid >> 6;
    const int wm = wave >> 1, wn = wave & 1;
    const int l15 = lane & 15, quad = lane >> 4;

    f32x4 acc[4][2];
    #pragma unroll
    for (int i = 0; i < 4; ++i)
        #pragma unroll
        for (int jj = 0; jj < 2; ++jj)
            acc[i][jj] = (f32x4){0.f, 0.f, 0.f, 0.f};

    for (int k0 = 0; k0 < DM; k0 += 64) {
        #pragma unroll
        for (int i = 0; i < 4; ++i) {
            int ch = tid + i * 256;           // [0,1024)
            int r = ch >> 3, jg = (ch & 7) ^ (r & 7);
            async16(xb + (m0 + r) * DM + k0 + jg * 8, Al + ch * 8);
        }
        #pragma unroll
        for (int i = 0; i < 2; ++i) {
            int ch = tid + i * 256;           // [0,512)
            int r = ch >> 3, jg = (ch & 7) ^ (r & 7);
            async16(w1t + (n0 + r) * DM + k0 + jg * 8, Bl + ch * 8);
        }
        __syncthreads();

        #pragma unroll
        for (int kk = 0; kk < 2; ++kk) {
            bf16x8 bfr[2];
            #pragma unroll
            for (int jj = 0; jj < 2; ++jj) {
                int rb = wn * 32 + jj * 16 + l15;
                int jb = (kk * 4 + quad) ^ (rb & 7);
                bfr[jj] = *(const bf16x8*)(Bl + rb * 64 + jb * 8);
            }
            #pragma unroll
            for (int i = 0; i < 4; ++i) {
                int rr = wm * 64 + i * 16 + l15;
                int ja = (kk * 4 + quad) ^ (rr & 7);
                bf16x8 af = *(const bf16x8*)(Al + rr * 64 + ja * 8);
                #pragma unroll
                for (int jj = 0; jj < 2; ++jj)
                    acc[i][jj] = __builtin_amdgcn_mfma_f32_16x16x32_bf16(
                        af, bfr[jj], acc[i][jj], 0, 0, 0);
            }
        }
        __syncthreads();
    }

    // epilogue: C/D layout col = lane&15, row = quad*4 + reg
    #pragma unroll
    for (int i = 0; i < 4; ++i) {
        const int rowbase = m0 + wm * 64 + i * 16 + quad * 4;
        float4 s4 = *(const float4*)(s_arr + rowbase);
        #pragma unroll
        for (int jj = 0; jj < 2; ++jj) {
            int gcol = n0 + wn * 32 + jj * 16 + l15;
            float bias = b1[gcol];
            #pragma unroll
            for (int r = 0; r < 4; ++r) {
                int grow = rowbase + r;
                float v = acc[i][jj][r] + bias;
                float sp = softplus_fast(v);
                float xv = bf2f(xb[grow * DM + gcol]);
                float sv = (r == 0) ? s4.x : (r == 1) ? s4.y : (r == 2) ? s4.z : s4.w;
                y[grow * DM + gcol] = xv * sp * sv;
            }
        }
    }
}

extern "C" void kernel_launch(void* const* d_in, const int* in_sizes, int n_in,
                              void* d_out, int out_size, void* d_ws, size_t ws_size,
                              hipStream_t stream) {
    const float* x  = (const float*)d_in[0];
    const float* W1 = (const float*)d_in[1];
    const float* b1 = (const float*)d_in[2];
    const float* W2 = (const float*)d_in[3];
    const float* b2 = (const float*)d_in[4];
    const float* W3 = (const float*)d_in[5];
    const float* b3 = (const float*)d_in[6];
    // d_in[7] = A : unused (multiplied by h0 == 0 in the reference)
    float* y = (float*)d_out;

    unsigned short* xb   = (unsigned short*)d_ws;                      // 12,582,912 B
    unsigned short* w1t  = (unsigned short*)((char*)d_ws + 12582912);  //  1,179,648 B
    unsigned short* w23t = (unsigned short*)((char*)d_ws + 13762560);  //     49,152 B
    float*          sarr = (float*)((char*)d_ws + 13811712);           //     32,768 B

    prep_kernel<<<6752, 256, 0, stream>>>(x, W1, W2, W3, xb, w1t, w23t);
    sgemm_kernel<<<128, 256, 0, stream>>>(xb, w23t, b2, b3, sarr);
    gemm_fused_kernel<<<768, 256, 0, stream>>>(xb, w1t, b1, sarr, y);
}